// Round 1
// baseline (158.108 us; speedup 1.0000x reference)
//
#include <hip/hip_runtime.h>
#include <stdint.h>

#define ALPHA 0.2f
#define LOG2E 1.4426950408889634f

typedef unsigned short u16;
typedef short s16x8 __attribute__((ext_vector_type(8)));   // 8 bf16 as shorts
typedef float f32x4 __attribute__((ext_vector_type(4)));

union BF8 { s16x8 v; uint32_t u[4]; u16 s[8]; uint4 q; };

static __device__ __forceinline__ float bf2f(u16 u) {
  union { uint32_t i; float f; } c; c.i = ((uint32_t)u) << 16; return c.f;
}
// round-to-nearest pack of two f32 -> packed bf16x2
static __device__ __forceinline__ uint32_t pk2bf(float lo, float hi) {
  uint32_t ul = __float_as_uint(lo) + 0x8000u;
  uint32_t uh = __float_as_uint(hi) + 0x8000u;
  return (ul >> 16) | (uh & 0xffff0000u);
}

// ------------- fallback: ws too small -> zero output (diagnostic) --------
__global__ __launch_bounds__(256) void k_zero(uint32_t* __restrict__ out, int n32) {
  int gid = blockIdx.x * 256 + threadIdx.x;
  if (gid < n32) out[gid] = 0u;
}

// ---------------- kernel 0: pack adj -> bitmask; block 0 also detects dtype
// grid-stride x8: 2048 blocks instead of 16384 (dispatch-ramp overhead)
__global__ __launch_bounds__(256) void k_pack_adj(const int* __restrict__ adj,
                                                  uint32_t* __restrict__ bits,
                                                  const u16* __restrict__ h,
                                                  int* __restrict__ flag) {
  int tid = threadIdx.x;
  int base = blockIdx.x * 256 + tid;
#pragma unroll
  for (int it = 0; it < 8; ++it) {
    int gid = base + it * (2048 * 256);
    unsigned long long m = __ballot(adj[gid] != 0);
    if ((tid & 63) == 0)
      *(unsigned long long*)(&bits[gid >> 5]) = m;
  }
  if (blockIdx.x == 0 && tid < 64) {   // wave 0: dtype vote (1=bf16, 0=fp32)
    u16 v = h[2 * tid];
    int e = (v >> 7) & 0xff;
    unsigned long long dm = __ballot(e >= 100 && e <= 140);
    if (tid == 0) flag[0] = (__popcll(dm) >= 48) ? 1 : 0;
  }
}

// ---------------- kernel 1: WhT = (h@W)^T per batch, + e_src/e_dst --------
// WhT: [8][128][2048] bf16 ; eS/eD: [8][2048] f32 (pre-scaled by log2e)
__global__ __launch_bounds__(256) void k_wh(
    const void* __restrict__ hV, const void* __restrict__ WgV,
    const void* __restrict__ aSrcV, const void* __restrict__ aDstV,
    const int* __restrict__ flag,
    u16* __restrict__ WhT, float* __restrict__ eS, float* __restrict__ eD) {
  __shared__ __align__(16) char smemRaw[34816];    // WT bf16[128][136] then f32 tile[64][130]
  u16*   WT   = (u16*)smemRaw;
  float* tile = (float*)smemRaw;
  __shared__ float aS[128], aD[128];

  const int tid = threadIdx.x;
  const int mb = blockIdx.x * 64;
  const int isBf = *flag;

  if (isBf) {
    const u16* Wg = (const u16*)WgV;
    for (int it = 0; it < 8; ++it) {
      int idx = tid + it * 256;
      int k = idx >> 4, c0 = (idx & 15) * 8;
      uint4 w4 = *(const uint4*)(Wg + (k << 7) + c0);
      u16* wsv = (u16*)&w4;
#pragma unroll
      for (int e = 0; e < 8; ++e) WT[(c0 + e) * 136 + k] = wsv[e];
    }
    if (tid < 128) aS[tid] = bf2f(((const u16*)aSrcV)[tid]);
    else           aD[tid - 128] = bf2f(((const u16*)aDstV)[tid - 128]);
  } else {
    const float* Wg = (const float*)WgV;
    for (int it = 0; it < 8; ++it) {
      int idx = tid + it * 256;
      int k = idx >> 4, c0 = (idx & 15) * 8;
      float4 w0 = *(const float4*)(Wg + (k << 7) + c0);
      float4 w1 = *(const float4*)(Wg + (k << 7) + c0 + 4);
      float wf[8] = {w0.x, w0.y, w0.z, w0.w, w1.x, w1.y, w1.z, w1.w};
#pragma unroll
      for (int e = 0; e < 8; ++e)
        WT[(c0 + e) * 136 + k] = (u16)((__float_as_uint(wf[e]) + 0x8000u) >> 16);
    }
    if (tid < 128) aS[tid] = ((const float*)aSrcV)[tid];
    else           aD[tid - 128] = ((const float*)aDstV)[tid - 128];
  }
  __syncthreads();

  const int wv = tid >> 6, lane = tid & 63, ln = lane & 15, quad = lane >> 4;
  const int row = mb + wv * 16 + ln;

  f32x4 acc[8];
#pragma unroll
  for (int t = 0; t < 8; ++t) acc[t] = (f32x4){0.f, 0.f, 0.f, 0.f};

  if (isBf) {
    const u16* h = (const u16*)hV;
#pragma unroll
    for (int ks = 0; ks < 4; ++ks) {
      s16x8 af = *(const s16x8*)(h + (row << 7) + ks * 32 + quad * 8);
#pragma unroll
      for (int t = 0; t < 8; ++t) {
        s16x8 bfg = *(const s16x8*)(&WT[(t * 16 + ln) * 136 + ks * 32 + quad * 8]);
        acc[t] = __builtin_amdgcn_mfma_f32_16x16x32_bf16(af, bfg, acc[t], 0, 0, 0);
      }
    }
  } else {
    const float* h = (const float*)hV;
#pragma unroll
    for (int ks = 0; ks < 4; ++ks) {
      float4 a0 = *(const float4*)(h + (row << 7) + ks * 32 + quad * 8);
      float4 a1 = *(const float4*)(h + (row << 7) + ks * 32 + quad * 8 + 4);
      BF8 af;
      af.u[0] = pk2bf(a0.x, a0.y);
      af.u[1] = pk2bf(a0.z, a0.w);
      af.u[2] = pk2bf(a1.x, a1.y);
      af.u[3] = pk2bf(a1.z, a1.w);
#pragma unroll
      for (int t = 0; t < 8; ++t) {
        s16x8 bfg = *(const s16x8*)(&WT[(t * 16 + ln) * 136 + ks * 32 + quad * 8]);
        acc[t] = __builtin_amdgcn_mfma_f32_16x16x32_bf16(af.v, bfg, acc[t], 0, 0, 0);
      }
    }
  }
  __syncthreads();                                   // done with WT; reuse as tile

  // D layout: row = quad*4+r, col = t*16+ln
#pragma unroll
  for (int t = 0; t < 8; ++t)
#pragma unroll
    for (int r = 0; r < 4; ++r)
      tile[(wv * 16 + quad * 4 + r) * 130 + t * 16 + ln] = acc[t][r];
  __syncthreads();

  if (tid < 128) {
    int r = tid & 63, grp = tid >> 6;
    const float* a = grp ? aD : aS;
    float sum = 0.f;
#pragma unroll 4
    for (int d = 0; d < 128; ++d) sum += tile[r * 130 + d] * a[d];
    int m = mb + r, b = m >> 11, n = m & 2047;
    (grp ? eD : eS)[(b << 11) + n] = sum * LOG2E;
  }

  // write WhT[b][d][n] (transposed bf16), 64B per thread
  {
    int d = tid >> 1, half = tid & 1;
    int n0 = mb & 2047, b = mb >> 11;
    uint32_t pk[16];
#pragma unroll
    for (int qq = 0; qq < 16; ++qq) {
      float v0 = tile[(half * 32 + 2 * qq) * 130 + d];
      float v1 = tile[(half * 32 + 2 * qq + 1) * 130 + d];
      pk[qq] = pk2bf(v0, v1);
    }
    uint4* dst = (uint4*)(WhT + (size_t)((b << 7) + d) * 2048 + n0 + half * 32);
#pragma unroll
    for (int c = 0; c < 4; ++c)
      dst[c] = make_uint4(pk[c * 4], pk[c * 4 + 1], pk[c * 4 + 2], pk[c * 4 + 3]);
  }
}

// ---------------- kernel 2: masked softmax(rank-1 logits) @ Wh ------------
// grid: 512 = b(8) x ig(64, 32 rows each); block 512 thr = 8 waves.
// wave = (s = wv&1: which 16-row half, jq = wv>>1: j-quarter of 512).
// Each wave: 16 rows x all 128 d x 512 j (16 steps). No exp duplication,
// no in-loop LDS/barriers (adj + eDst straight from L1/L2). j-partials
// merged once in an LDS epilogue. 2 blocks/CU -> 16 waves/CU.
__global__ __launch_bounds__(512, 4) void k_attn(
    const u16* __restrict__ WhT, const float* __restrict__ eSrc,
    const float* __restrict__ eDst, const uint32_t* __restrict__ adjBits,
    const int* __restrict__ flag, void* __restrict__ outV) {
  __shared__ __align__(16) float mrgT[2][3][128][16];  // 48 KB, epilogue only
  __shared__ float den2[2][4][16];
  __shared__ uint2 mlut[16];                           // nibble -> bf16x2 AND masks

  const int tid = threadIdx.x;
  // XCD swizzle: 512 % 8 == 0, b == XCD id -> each XCD L2 holds one WhT[b]
  const int bid = (blockIdx.x & 7) * 64 + (blockIdx.x >> 3);
  const int b = bid >> 6, ig = bid & 63;
  const int i0 = ig * 32;

  if (tid < 16) {
    uint32_t lo = ((tid & 1) ? 0xffffu : 0u) | ((tid & 2) ? 0xffff0000u : 0u);
    uint32_t hi = ((tid & 4) ? 0xffffu : 0u) | ((tid & 8) ? 0xffff0000u : 0u);
    mlut[tid] = make_uint2(lo, hi);
  }
  __syncthreads();

  const int wv = tid >> 6, lane = tid & 63, ln = lane & 15, quad = lane >> 4;
  const int s = wv & 1, jq = wv >> 1;
  const int row16 = i0 + s * 16;

  const float sS = eSrc[(b << 11) + row16 + ln];
  const uint32_t* adjP = adjBits + (((size_t)(row16 + ln)) << 6) + jq * 16;
  const float* eDp = eDst + (b << 11) + jq * 512 + quad * 8;
  // WhT row (d) stride = 2048*2 = 4096 B; batch stride = 128*4096 = 1<<19 B
  const char* whB = (const char*)WhT + ((size_t)b << 19)
                  + ((uint32_t)ln << 12) + quad * 16 + jq * 1024;

  f32x4 acc[8], accD;
#pragma unroll
  for (int t = 0; t < 8; ++t) acc[t] = (f32x4){0.f, 0.f, 0.f, 0.f};
  accD = (f32x4){0.f, 0.f, 0.f, 0.f};

  BF8 ones;
  ones.u[0] = 0x3f803f80u; ones.u[1] = 0x3f803f80u;
  ones.u[2] = 0x3f803f80u; ones.u[3] = 0x3f803f80u;

  for (int step = 0; step < 16; ++step) {
    uint32_t aw = adjP[step];                       // 16 rows x quad-broadcast, L1
    uint32_t mby = (aw >> (quad * 8)) & 0xffu;
    uint2 mlo = mlut[mby & 15u];                    // fetched early, off exp chain
    uint2 mhi = mlut[mby >> 4];
    f32x4 d0 = *(const f32x4*)(eDp + step * 32);
    f32x4 d1 = *(const f32x4*)(eDp + step * 32 + 4);
    BF8 bfr[8];
#pragma unroll
    for (int tt = 0; tt < 8; ++tt)
      bfr[tt].q = *(const uint4*)(whB + tt * 65536 + step * 64);

    float p[8];
#pragma unroll
    for (int jj = 0; jj < 8; ++jj) {
      float x = sS + (jj < 4 ? d0[jj] : d1[jj - 4]);
      float l = __builtin_amdgcn_fmed3f(x, ALPHA * x, 80.f);  // leakyrelu + guard
      p[jj] = exp2f(l);
    }
    BF8 af;
    af.u[0] = pk2bf(p[0], p[1]) & mlo.x;            // mask = AND on packed bf16
    af.u[1] = pk2bf(p[2], p[3]) & mlo.y;
    af.u[2] = pk2bf(p[4], p[5]) & mhi.x;
    af.u[3] = pk2bf(p[6], p[7]) & mhi.y;

    accD = __builtin_amdgcn_mfma_f32_16x16x32_bf16(af.v, ones.v, accD, 0, 0, 0);
#pragma unroll
    for (int tt = 0; tt < 8; ++tt)
      acc[tt] = __builtin_amdgcn_mfma_f32_16x16x32_bf16(af.v, bfr[tt].v, acc[tt], 0, 0, 0);
  }

  // ---- epilogue: merge j-quarters in LDS, normalize, store ----
  if (jq != 0) {
#pragma unroll
    for (int tt = 0; tt < 8; ++tt)
      *(f32x4*)&mrgT[s][jq - 1][tt * 16 + ln][quad * 4] = acc[tt];
  }
  if (ln == 0) {
#pragma unroll
    for (int r = 0; r < 4; ++r) den2[s][jq][quad * 4 + r] = accD[r];
  }
  __syncthreads();

  if (jq == 0) {
#pragma unroll
    for (int tt = 0; tt < 8; ++tt) {
#pragma unroll
      for (int pq = 0; pq < 3; ++pq) {
        f32x4 m = *(const f32x4*)&mrgT[s][pq][tt * 16 + ln][quad * 4];
        acc[tt] += m;
      }
    }
    float inv[4];
#pragma unroll
    for (int r = 0; r < 4; ++r) {
      float den = den2[s][0][quad * 4 + r] + den2[s][1][quad * 4 + r]
                + den2[s][2][quad * 4 + r] + den2[s][3][quad * 4 + r];
      inv[r] = 1.0f / fmaxf(den, 1e-37f);
    }
    const int isBf = *flag;
    if (isBf) {
      u16* outp = (u16*)outV;
#pragma unroll
      for (int tt = 0; tt < 8; ++tt)
#pragma unroll
        for (int r = 0; r < 4; ++r) {
          size_t off = ((size_t)((b << 11) + row16 + quad * 4 + r) << 7)
                     + tt * 16 + ln;
          float v = acc[tt][r] * inv[r];
          outp[off] = (u16)((__float_as_uint(v) + 0x8000u) >> 16);
        }
    } else {
      float* outp = (float*)outV;
#pragma unroll
      for (int tt = 0; tt < 8; ++tt)
#pragma unroll
        for (int r = 0; r < 4; ++r) {
          size_t off = ((size_t)((b << 11) + row16 + quad * 4 + r) << 7)
                     + tt * 16 + ln;
          outp[off] = acc[tt][r] * inv[r];
        }
    }
  }
}

extern "C" void kernel_launch(void* const* d_in, const int* in_sizes, int n_in,
                              void* d_out, int out_size, void* d_ws, size_t ws_size,
                              hipStream_t stream) {
  const void* h   = d_in[0];
  const int* adj  = (const int*)d_in[1];
  const void* Wg  = d_in[2];
  const void* aS  = d_in[3];
  const void* aD  = d_in[4];

  const size_t OFF_ES   = (size_t)4 << 20;               // 4 MB WhT
  const size_t OFF_ED   = OFF_ES + (64 << 10);
  const size_t OFF_BITS = OFF_ED + (64 << 10);
  const size_t OFF_FLAG = OFF_BITS + (512 << 10);
  const size_t NEEDED   = OFF_FLAG + 64;

  if (ws_size < NEEDED) {
    int n32 = out_size / 2;
    k_zero<<<(n32 + 255) / 256, 256, 0, stream>>>((uint32_t*)d_out, n32);
    return;
  }

  char* ws = (char*)d_ws;
  u16* WhT      = (u16*)ws;
  float* eSp    = (float*)(ws + OFF_ES);
  float* eDp    = (float*)(ws + OFF_ED);
  uint32_t* bit = (uint32_t*)(ws + OFF_BITS);
  int* flag     = (int*)(ws + OFF_FLAG);

  k_pack_adj<<<2048, 256, 0, stream>>>(adj, bit, (const u16*)h, flag);
  k_wh<<<256, 256, 0, stream>>>(h, Wg, aS, aD, flag, WhT, eSp, eDp);
  k_attn<<<512, 512, 0, stream>>>(WhT, eSp, eDp, bit, flag, d_out);
}

// Round 2
// 118.959 us; speedup vs baseline: 1.3291x; 1.3291x over previous
//
#include <hip/hip_runtime.h>
#include <stdint.h>

#define ALPHA 0.2f
#define LOG2E 1.4426950408889634f

typedef unsigned short u16;
typedef short s16x8 __attribute__((ext_vector_type(8)));   // 8 bf16 as shorts
typedef float f32x4 __attribute__((ext_vector_type(4)));

union BF8 { s16x8 v; uint32_t u[4]; u16 s[8]; uint4 q; };

static __device__ __forceinline__ float bf2f(u16 u) {
  union { uint32_t i; float f; } c; c.i = ((uint32_t)u) << 16; return c.f;
}
// round-to-nearest pack of two f32 -> packed bf16x2
static __device__ __forceinline__ uint32_t pk2bf(float lo, float hi) {
  uint32_t ul = __float_as_uint(lo) + 0x8000u;
  uint32_t uh = __float_as_uint(hi) + 0x8000u;
  return (ul >> 16) | (uh & 0xffff0000u);
}

// async global->LDS, 16B per lane; lds dest must be wave-uniform base
static __device__ __forceinline__ void gl2lds16(const void* g, void* l) {
  __builtin_amdgcn_global_load_lds(
      (const __attribute__((address_space(1))) uint32_t*)g,
      (__attribute__((address_space(3))) uint32_t*)l, 16, 0, 0);
}

// ------------- fallback: ws too small -> zero output (diagnostic) --------
__global__ __launch_bounds__(256) void k_zero(uint32_t* __restrict__ out, int n32) {
  int gid = blockIdx.x * 256 + threadIdx.x;
  if (gid < n32) out[gid] = 0u;
}

// ---------------- kernel 0: pack adj -> bitmask; block 0 also detects dtype
__global__ __launch_bounds__(256) void k_pack_adj(const int* __restrict__ adj,
                                                  uint32_t* __restrict__ bits,
                                                  const u16* __restrict__ h,
                                                  int* __restrict__ flag) {
  int tid = threadIdx.x;
  int base = blockIdx.x * 256 + tid;
#pragma unroll
  for (int it = 0; it < 8; ++it) {
    int gid = base + it * (2048 * 256);
    unsigned long long m = __ballot(adj[gid] != 0);
    if ((tid & 63) == 0)
      *(unsigned long long*)(&bits[gid >> 5]) = m;
  }
  if (blockIdx.x == 0 && tid < 64) {   // wave 0: dtype vote (1=bf16, 0=fp32)
    u16 v = h[2 * tid];
    int e = (v >> 7) & 0xff;
    unsigned long long dm = __ballot(e >= 100 && e <= 140);
    if (tid == 0) flag[0] = (__popcll(dm) >= 48) ? 1 : 0;
  }
}

// ---------------- kernel 1: WhT = (h@W)^T per batch, + e_src/e_dst --------
// WhT: [8][128][2048] bf16 ; eS/eD: [8][2048] f32 (pre-scaled by log2e)
__global__ __launch_bounds__(256) void k_wh(
    const void* __restrict__ hV, const void* __restrict__ WgV,
    const void* __restrict__ aSrcV, const void* __restrict__ aDstV,
    const int* __restrict__ flag,
    u16* __restrict__ WhT, float* __restrict__ eS, float* __restrict__ eD) {
  __shared__ __align__(16) char smemRaw[34816];    // WT bf16[128][136] then f32 tile[64][130]
  u16*   WT   = (u16*)smemRaw;
  float* tile = (float*)smemRaw;
  __shared__ float aS[128], aD[128];

  const int tid = threadIdx.x;
  const int mb = blockIdx.x * 64;
  const int isBf = *flag;

  if (isBf) {
    const u16* Wg = (const u16*)WgV;
    for (int it = 0; it < 8; ++it) {
      int idx = tid + it * 256;
      int k = idx >> 4, c0 = (idx & 15) * 8;
      uint4 w4 = *(const uint4*)(Wg + (k << 7) + c0);
      u16* wsv = (u16*)&w4;
#pragma unroll
      for (int e = 0; e < 8; ++e) WT[(c0 + e) * 136 + k] = wsv[e];
    }
    if (tid < 128) aS[tid] = bf2f(((const u16*)aSrcV)[tid]);
    else           aD[tid - 128] = bf2f(((const u16*)aDstV)[tid - 128]);
  } else {
    const float* Wg = (const float*)WgV;
    for (int it = 0; it < 8; ++it) {
      int idx = tid + it * 256;
      int k = idx >> 4, c0 = (idx & 15) * 8;
      float4 w0 = *(const float4*)(Wg + (k << 7) + c0);
      float4 w1 = *(const float4*)(Wg + (k << 7) + c0 + 4);
      float wf[8] = {w0.x, w0.y, w0.z, w0.w, w1.x, w1.y, w1.z, w1.w};
#pragma unroll
      for (int e = 0; e < 8; ++e)
        WT[(c0 + e) * 136 + k] = (u16)((__float_as_uint(wf[e]) + 0x8000u) >> 16);
    }
    if (tid < 128) aS[tid] = ((const float*)aSrcV)[tid];
    else           aD[tid - 128] = ((const float*)aDstV)[tid - 128];
  }
  __syncthreads();

  const int wv = tid >> 6, lane = tid & 63, ln = lane & 15, quad = lane >> 4;
  const int row = mb + wv * 16 + ln;

  f32x4 acc[8];
#pragma unroll
  for (int t = 0; t < 8; ++t) acc[t] = (f32x4){0.f, 0.f, 0.f, 0.f};

  if (isBf) {
    const u16* h = (const u16*)hV;
#pragma unroll
    for (int ks = 0; ks < 4; ++ks) {
      s16x8 af = *(const s16x8*)(h + (row << 7) + ks * 32 + quad * 8);
#pragma unroll
      for (int t = 0; t < 8; ++t) {
        s16x8 bfg = *(const s16x8*)(&WT[(t * 16 + ln) * 136 + ks * 32 + quad * 8]);
        acc[t] = __builtin_amdgcn_mfma_f32_16x16x32_bf16(af, bfg, acc[t], 0, 0, 0);
      }
    }
  } else {
    const float* h = (const float*)hV;
#pragma unroll
    for (int ks = 0; ks < 4; ++ks) {
      float4 a0 = *(const float4*)(h + (row << 7) + ks * 32 + quad * 8);
      float4 a1 = *(const float4*)(h + (row << 7) + ks * 32 + quad * 8 + 4);
      BF8 af;
      af.u[0] = pk2bf(a0.x, a0.y);
      af.u[1] = pk2bf(a0.z, a0.w);
      af.u[2] = pk2bf(a1.x, a1.y);
      af.u[3] = pk2bf(a1.z, a1.w);
#pragma unroll
      for (int t = 0; t < 8; ++t) {
        s16x8 bfg = *(const s16x8*)(&WT[(t * 16 + ln) * 136 + ks * 32 + quad * 8]);
        acc[t] = __builtin_amdgcn_mfma_f32_16x16x32_bf16(af.v, bfg, acc[t], 0, 0, 0);
      }
    }
  }
  __syncthreads();                                   // done with WT; reuse as tile

  // D layout: row = quad*4+r, col = t*16+ln
#pragma unroll
  for (int t = 0; t < 8; ++t)
#pragma unroll
    for (int r = 0; r < 4; ++r)
      tile[(wv * 16 + quad * 4 + r) * 130 + t * 16 + ln] = acc[t][r];
  __syncthreads();

  if (tid < 128) {
    int r = tid & 63, grp = tid >> 6;
    const float* a = grp ? aD : aS;
    float sum = 0.f;
#pragma unroll 4
    for (int d = 0; d < 128; ++d) sum += tile[r * 130 + d] * a[d];
    int m = mb + r, b = m >> 11, n = m & 2047;
    (grp ? eD : eS)[(b << 11) + n] = sum * LOG2E;
  }

  // write WhT[b][d][n] (transposed bf16), 64B per thread
  {
    int d = tid >> 1, half = tid & 1;
    int n0 = mb & 2047, b = mb >> 11;
    uint32_t pk[16];
#pragma unroll
    for (int qq = 0; qq < 16; ++qq) {
      float v0 = tile[(half * 32 + 2 * qq) * 130 + d];
      float v1 = tile[(half * 32 + 2 * qq + 1) * 130 + d];
      pk[qq] = pk2bf(v0, v1);
    }
    uint4* dst = (uint4*)(WhT + (size_t)((b << 7) + d) * 2048 + n0 + half * 32);
#pragma unroll
    for (int c = 0; c < 4; ++c)
      dst[c] = make_uint4(pk[c * 4], pk[c * 4 + 1], pk[c * 4 + 2], pk[c * 4 + 3]);
  }
}

// ---------------- kernel 2: masked softmax(rank-1 logits) @ Wh ------------
// grid: 512 = b(8) x ig(64, 32 rows); block 512 thr = 8 waves.
// Double-buffered LDS pipeline over 32 j-tiles of 64:
//   B-tile  (WhT 128d x 64j, 16KB) staged via global_load_lds, XOR-swizzled
//           through pre-swizzled global source addresses (granule ^ (d&7)).
//   P-tile  (32i x 64j masked exp bf16, 4KB) computed cooperatively once
//           (4 exps/thread) and ds_write_b64'd with the same XOR family.
// Waves split (s: 16-row half) x (dh: 32-d quarter) -> each wave owns its
// 16x32 output patch; no exp duplication, no j-merge. One barrier / tile.
__global__ __launch_bounds__(512, 4) void k_attn(
    const u16* __restrict__ WhT, const float* __restrict__ eSrc,
    const float* __restrict__ eDst, const uint32_t* __restrict__ adjBits,
    const int* __restrict__ flag, void* __restrict__ outV) {
  __shared__ __align__(16) u16 bufB[2][8192];   // 2 x 16KB  [128 d][64 j]
  __shared__ __align__(16) u16 bufP[2][2048];   // 2 x 4KB   [32 i][64 j]; den after loop

  const int tid = threadIdx.x;
  // XCD swizzle: 512 % 8 == 0, b == XCD id -> each XCD L2 holds one WhT[b]
  const int bid = (blockIdx.x & 7) * 64 + (blockIdx.x >> 3);
  const int b = bid >> 6, ig = bid & 63;
  const int i0 = ig * 32;

  const int w = tid >> 6, l = tid & 63;
  const int ln = l & 15, quad = l >> 4;
  const int s = w & 1, dh = w >> 1;

  // ---- staging constants (B tile) ----
  // lane l covers d = it*64 + w*8 + (l>>3), physical granule p = l&7;
  // source logical granule = p ^ (d&7) = (l&7) ^ ((l>>3)&7)
  const int gsrc = (l & 7) ^ ((l >> 3) & 7);
  const u16* whtB = WhT + ((size_t)b << 18);
  const u16* srcB = whtB + (size_t)(w * 8 + (l >> 3)) * 2048 + gsrc * 8;

  // ---- P producer constants ----
  const int prow = tid >> 4, hg = tid & 15;       // row 0..31, 4-j group 0..15
  const float sSp = eSrc[(b << 11) + i0 + prow];
  const float* eDb = eDst + (b << 11) + hg * 4;
  const uint32_t* adjB = adjBits + (size_t)(i0 + prow) * 64 + (hg >> 3);
  const int pOff = prow * 128 + ((hg ^ ((prow & 7) << 1)) * 8);   // bytes

  // ---- consumer LDS offsets (bytes) ----
  int aOff[2], bOff[2][2];
#pragma unroll
  for (int jk = 0; jk < 2; ++jk) {
    aOff[jk] = (s * 16 + ln) * 128 + (((jk * 4 + quad) ^ (ln & 7)) * 16);
#pragma unroll
    for (int tt = 0; tt < 2; ++tt)
      bOff[tt][jk] = (dh * 32 + tt * 16 + ln) * 128
                   + (((jk * 4 + quad) ^ (ln & 7)) * 16);
  }

  f32x4 acc[2], accD;
  acc[0] = (f32x4){0.f, 0.f, 0.f, 0.f};
  acc[1] = (f32x4){0.f, 0.f, 0.f, 0.f};
  accD   = (f32x4){0.f, 0.f, 0.f, 0.f};

  BF8 ones;
  ones.u[0] = 0x3f803f80u; ones.u[1] = 0x3f803f80u;
  ones.u[2] = 0x3f803f80u; ones.u[3] = 0x3f803f80u;

  u16 *bBc = bufB[0], *bBn = bufB[1];
  u16 *bPc = bufP[0], *bPn = bufP[1];

  // ---- prologue: stage tile 0 ----
  gl2lds16(srcB, bBc + w * 512);
  gl2lds16(srcB + 131072, bBc + 4096 + w * 512);
  {
    f32x4 dv = *(const f32x4*)(eDb);
    uint32_t aw = adjB[0];
    uint32_t nib = (aw >> ((hg & 7) * 4)) & 0xfu;
    float x0 = sSp + dv[0], x1 = sSp + dv[1], x2 = sSp + dv[2], x3 = sSp + dv[3];
    float p0 = exp2f(__builtin_amdgcn_fmed3f(x0, ALPHA * x0, 80.f));
    float p1 = exp2f(__builtin_amdgcn_fmed3f(x1, ALPHA * x1, 80.f));
    float p2 = exp2f(__builtin_amdgcn_fmed3f(x2, ALPHA * x2, 80.f));
    float p3 = exp2f(__builtin_amdgcn_fmed3f(x3, ALPHA * x3, 80.f));
    uint32_t m01 = ((nib & 1u) ? 0x0000ffffu : 0u) | ((nib & 2u) ? 0xffff0000u : 0u);
    uint32_t m23 = ((nib & 4u) ? 0x0000ffffu : 0u) | ((nib & 8u) ? 0xffff0000u : 0u);
    *(uint2*)((char*)bPc + pOff) = make_uint2(pk2bf(p0, p1) & m01,
                                              pk2bf(p2, p3) & m23);
  }
  __syncthreads();

  for (int t = 0; t < 32; ++t) {
    if (t + 1 < 32) {
      // stage B[t+1]
      gl2lds16(srcB + (size_t)(t + 1) * 64, bBn + w * 512);
      gl2lds16(srcB + (size_t)(t + 1) * 64 + 131072, bBn + 4096 + w * 512);
      // compute P[t+1]
      f32x4 dv = *(const f32x4*)(eDb + (t + 1) * 64);
      uint32_t aw = adjB[(t + 1) * 2];
      uint32_t nib = (aw >> ((hg & 7) * 4)) & 0xfu;
      float x0 = sSp + dv[0], x1 = sSp + dv[1], x2 = sSp + dv[2], x3 = sSp + dv[3];
      float p0 = exp2f(__builtin_amdgcn_fmed3f(x0, ALPHA * x0, 80.f));
      float p1 = exp2f(__builtin_amdgcn_fmed3f(x1, ALPHA * x1, 80.f));
      float p2 = exp2f(__builtin_amdgcn_fmed3f(x2, ALPHA * x2, 80.f));
      float p3 = exp2f(__builtin_amdgcn_fmed3f(x3, ALPHA * x3, 80.f));
      uint32_t m01 = ((nib & 1u) ? 0x0000ffffu : 0u) | ((nib & 2u) ? 0xffff0000u : 0u);
      uint32_t m23 = ((nib & 4u) ? 0x0000ffffu : 0u) | ((nib & 8u) ? 0xffff0000u : 0u);
      *(uint2*)((char*)bPn + pOff) = make_uint2(pk2bf(p0, p1) & m01,
                                                pk2bf(p2, p3) & m23);
    }

    // consume tile t from cur buffers
    s16x8 af0 = *(const s16x8*)((const char*)bPc + aOff[0]);
    s16x8 af1 = *(const s16x8*)((const char*)bPc + aOff[1]);
    s16x8 b00 = *(const s16x8*)((const char*)bBc + bOff[0][0]);
    s16x8 b10 = *(const s16x8*)((const char*)bBc + bOff[1][0]);
    s16x8 b01 = *(const s16x8*)((const char*)bBc + bOff[0][1]);
    s16x8 b11 = *(const s16x8*)((const char*)bBc + bOff[1][1]);

    __builtin_amdgcn_s_setprio(1);
    acc[0] = __builtin_amdgcn_mfma_f32_16x16x32_bf16(af0, b00, acc[0], 0, 0, 0);
    acc[1] = __builtin_amdgcn_mfma_f32_16x16x32_bf16(af0, b10, acc[1], 0, 0, 0);
    acc[0] = __builtin_amdgcn_mfma_f32_16x16x32_bf16(af1, b01, acc[0], 0, 0, 0);
    acc[1] = __builtin_amdgcn_mfma_f32_16x16x32_bf16(af1, b11, acc[1], 0, 0, 0);
    if (dh == 0) {
      accD = __builtin_amdgcn_mfma_f32_16x16x32_bf16(af0, ones.v, accD, 0, 0, 0);
      accD = __builtin_amdgcn_mfma_f32_16x16x32_bf16(af1, ones.v, accD, 0, 0, 0);
    }
    __builtin_amdgcn_s_setprio(0);

    __syncthreads();          // next buffers complete; cur reads done
    u16* tB = bBc; bBc = bBn; bBn = tB;
    u16* tP = bPc; bPc = bPn; bPn = tP;
  }

  // ---- epilogue: share denominators via LDS (reuse bufP), normalize ----
  float* den = (float*)bufP;
  if (dh == 0 && ln == 0) {
#pragma unroll
    for (int r = 0; r < 4; ++r) den[s * 16 + quad * 4 + r] = accD[r];
  }
  __syncthreads();

  float inv[4];
#pragma unroll
  for (int r = 0; r < 4; ++r)
    inv[r] = 1.0f / fmaxf(den[s * 16 + quad * 4 + r], 1e-37f);

  const int isBf = *flag;
  if (isBf) {
    u16* outp = (u16*)outV;
#pragma unroll
    for (int tt = 0; tt < 2; ++tt)
#pragma unroll
      for (int r = 0; r < 4; ++r) {
        size_t off = ((size_t)((b << 11) + i0 + s * 16 + quad * 4 + r) << 7)
                   + dh * 32 + tt * 16 + ln;
        float v = acc[tt][r] * inv[r];
        outp[off] = (u16)((__float_as_uint(v) + 0x8000u) >> 16);
      }
  } else {
    float* outp = (float*)outV;
#pragma unroll
    for (int tt = 0; tt < 2; ++tt)
#pragma unroll
      for (int r = 0; r < 4; ++r) {
        size_t off = ((size_t)((b << 11) + i0 + s * 16 + quad * 4 + r) << 7)
                   + dh * 32 + tt * 16 + ln;
        outp[off] = acc[tt][r] * inv[r];
      }
  }
}

extern "C" void kernel_launch(void* const* d_in, const int* in_sizes, int n_in,
                              void* d_out, int out_size, void* d_ws, size_t ws_size,
                              hipStream_t stream) {
  const void* h   = d_in[0];
  const int* adj  = (const int*)d_in[1];
  const void* Wg  = d_in[2];
  const void* aS  = d_in[3];
  const void* aD  = d_in[4];

  const size_t OFF_ES   = (size_t)4 << 20;               // 4 MB WhT
  const size_t OFF_ED   = OFF_ES + (64 << 10);
  const size_t OFF_BITS = OFF_ED + (64 << 10);
  const size_t OFF_FLAG = OFF_BITS + (512 << 10);
  const size_t NEEDED   = OFF_FLAG + 64;

  if (ws_size < NEEDED) {
    int n32 = out_size / 2;
    k_zero<<<(n32 + 255) / 256, 256, 0, stream>>>((uint32_t*)d_out, n32);
    return;
  }

  char* ws = (char*)d_ws;
  u16* WhT      = (u16*)ws;
  float* eSp    = (float*)(ws + OFF_ES);
  float* eDp    = (float*)(ws + OFF_ED);
  uint32_t* bit = (uint32_t*)(ws + OFF_BITS);
  int* flag     = (int*)(ws + OFF_FLAG);

  k_pack_adj<<<2048, 256, 0, stream>>>(adj, bit, (const u16*)h, flag);
  k_wh<<<256, 256, 0, stream>>>(h, Wg, aS, aD, flag, WhT, eSp, eDp);
  k_attn<<<512, 512, 0, stream>>>(WhT, eSp, eDp, bit, flag, d_out);
}